// Round 1
// baseline (2459.469 us; speedup 1.0000x reference)
//
#include <hip/hip_runtime.h>
#include <stdint.h>

#define NN 8192

typedef unsigned short u16;
typedef __attribute__((ext_vector_type(8))) short bf16x8;
typedef __attribute__((ext_vector_type(4))) float f32x4;

#define MFMA(a,b,c) __builtin_amdgcn_mfma_f32_16x16x32_bf16(a,b,c,0,0,0)

__device__ __forceinline__ u16 f2bf(float f) {
    uint32_t u = __float_as_uint(f);
    u += 0x7fffu + ((u >> 16) & 1u);
    return (u16)(u >> 16);
}

// ---------------- A fp32 -> bf16 ----------------
__global__ __launch_bounds__(256) void k_cvtA(const float4* __restrict__ A, u16* __restrict__ Abf) {
    size_t i = (size_t)blockIdx.x * blockDim.x + threadIdx.x;
    const size_t n4 = (size_t)NN * NN / 4;
    const size_t stride = (size_t)gridDim.x * blockDim.x;
    for (; i < n4; i += stride) {
        float4 v = A[i];
        union { u16 u[4]; uint2 q; } o;
        o.u[0] = f2bf(v.x); o.u[1] = f2bf(v.y); o.u[2] = f2bf(v.z); o.u[3] = f2bf(v.w);
        *(uint2*)(Abf + i * 4) = o.q;
    }
}

// ---------------- weight prep: W1T[o][k], W2T[d][o] bf16 + c = mlp(0) vectors ----------------
__global__ __launch_bounds__(256) void k_prep(
    const float* WA1, const float* WB1, const float* WD1, const float* WE1,
    const float* WA2, const float* WB2, const float* WD2, const float* WE2,
    const float* bA1, const float* bA2, const float* bE1, const float* bE2,
    u16* __restrict__ W1T, u16* __restrict__ W2T, float* __restrict__ cvec)
{
    const float* W1[4] = {WA1, WB1, WD1, WE1};
    const float* W2[4] = {WA2, WB2, WD2, WE2};
    int t = threadIdx.x;
    for (int m = 0; m < 4; ++m) {
        for (int idx = t; idx < 128 * 64; idx += 256) {
            int o = idx >> 6, k = idx & 63;
            W1T[m * 8192 + idx] = f2bf(W1[m][k * 128 + o]);       // W1T[o][k] = W1[k][o]
        }
        for (int idx = t; idx < 64 * 128; idx += 256) {
            int d = idx >> 7, o = idx & 127;
            W2T[m * 8192 + idx] = f2bf(W2[m][o * 64 + d]);        // W2T[d][o] = W2[o][d]
        }
    }
    if (t < 64) {
        float s = 0.f;
        for (int o = 0; o < 128; ++o) s += fmaxf(bA1[o], 0.f) * WA2[o * 64 + t];
        cvec[t] = s + bA2[t];
    } else if (t < 128) {
        int d = t - 64;
        float s = 0.f;
        for (int o = 0; o < 128; ++o) s += fmaxf(bE1[o], 0.f) * WE2[o * 64 + d];
        cvec[64 + d] = s + bE2[d];
    }
}

// ---------------- wave-local transposed bf16 store helper ----------------
// v[4] in MFMA C-layout (row=(lane>>4)*4+r over 16 rows, col=d*16+(lane&15) over 64 cols)
// writes bf16 to dst[g][col][n0+row]  (dst layout [..][64][NN])
__device__ __forceinline__ void storeT16(u16* __restrict__ dst, int g, int n0,
                                         u16* __restrict__ my, int lane, int l15, int l4,
                                         const f32x4 v[4])
{
#pragma unroll
    for (int d = 0; d < 4; ++d) {
        int col = d * 16 + l15;
#pragma unroll
        for (int r = 0; r < 4; ++r) {
            int row = l4 * 4 + r;
            my[col * 16 + row] = f2bf(v[d][r]);
        }
    }
    asm volatile("s_waitcnt lgkmcnt(0)" ::: "memory");
    int c = lane;
    uint4 v0 = *(const uint4*)(my + c * 16);
    uint4 v1 = *(const uint4*)(my + c * 16 + 8);
    u16* dp = dst + (size_t)(g * 64 + c) * NN + n0;
    *(uint4*)(dp)     = v0;
    *(uint4*)(dp + 8) = v1;
}

// ---------------- x_c -> xT (bf16 transposed) ----------------
__global__ __launch_bounds__(256) void k_trX(const float* __restrict__ x, u16* __restrict__ xT)
{
    __shared__ __align__(16) u16 sl[4][1024];
    int tid = threadIdx.x, lane = tid & 63, wid = tid >> 6;
    int l15 = lane & 15, l4 = lane >> 4;
    int g = blockIdx.y;
    int n0 = blockIdx.x * 64 + wid * 16;
    f32x4 v[4];
#pragma unroll
    for (int d = 0; d < 4; ++d)
#pragma unroll
        for (int r = 0; r < 4; ++r)
            v[d][r] = x[((size_t)g * NN + n0 + l4 * 4 + r) * 64 + d * 16 + l15];
    storeT16(xT, g, n0, sl[wid], lane, l15, l4, v);
}

// ---------------- main GEMM: T[g][i][d] = sum_k Abf[i][k] * X[g][d][k] ----------------
// X layout [G][64][NN] (transposed state), T layout [G][NN][64] fp32.
// grid: x = NN/64 row-blocks, y = pair index (groups 2y, 2y+1)
__global__ __launch_bounds__(256) void k_gemm(
    const u16* __restrict__ Abf, const u16* __restrict__ X, float* __restrict__ T)
{
    __shared__ __align__(16) u16 lds[2][3][4096];
    const int tid = threadIdx.x;
    const int lane = tid & 63, wid = tid >> 6;
    const int wr = wid >> 1, wc = wid & 1;
    const int l15 = lane & 15, l4 = lane >> 4;
    const int bx = blockIdx.x, g0 = blockIdx.y * 2;

    // staging: thread t, op j covers tile byte f=j*4096+t*16 -> row r=f/128, phys chunk cp=t&7.
    // source pre-swizzled: global chunk clog = cp ^ (r&7); LDS dest linear.
    size_t gA[2], gX0[2], gX1[2];
#pragma unroll
    for (int j = 0; j < 2; ++j) {
        int r = j * 32 + (tid >> 3);
        int clog = (tid & 7) ^ (r & 7);
        gA[j]  = (size_t)(bx * 64 + r) * NN + clog * 8;
        gX0[j] = (size_t)((g0 + 0) * 64 + r) * NN + clog * 8;
        gX1[j] = (size_t)((g0 + 1) * 64 + r) * NN + clog * 8;
    }
    const int wofs = tid * 8;  // ushort offset, linear dest

    int cs[2];
#pragma unroll
    for (int ks = 0; ks < 2; ++ks)
        cs[ks] = (((ks * 4 + l4) ^ (l15 & 7)) << 3);   // swizzled chunk, ushort units
    int arow[2], brow[4];
    arow[0] = (wr * 32 + l15) * 64; arow[1] = arow[0] + 16 * 64;
#pragma unroll
    for (int f = 0; f < 4; ++f) brow[f] = (f * 16 + l15) * 64;

    const f32x4 fz = {0.f, 0.f, 0.f, 0.f};
    f32x4 acc[2][4];
#pragma unroll
    for (int m = 0; m < 2; ++m)
#pragma unroll
        for (int f = 0; f < 4; ++f) acc[m][f] = fz;

    uint4 sA[2], s0[2], s1[2];
#pragma unroll
    for (int j = 0; j < 2; ++j) {
        sA[j] = *(const uint4*)(Abf + gA[j]);
        s0[j] = *(const uint4*)(X + gX0[j]);
        s1[j] = *(const uint4*)(X + gX1[j]);
    }
#pragma unroll
    for (int j = 0; j < 2; ++j) {
        *(uint4*)(&lds[0][0][j * 2048 + wofs]) = sA[j];
        *(uint4*)(&lds[0][1][j * 2048 + wofs]) = s0[j];
        *(uint4*)(&lds[0][2][j * 2048 + wofs]) = s1[j];
    }
    __syncthreads();

    int cur = 0;
    for (int step = 0; step < 128; ++step) {
        const bool more = (step < 127);
        if (more) {
            const int k0 = (step + 1) << 6;
#pragma unroll
            for (int j = 0; j < 2; ++j) {
                sA[j] = *(const uint4*)(Abf + gA[j] + k0);
                s0[j] = *(const uint4*)(X + gX0[j] + k0);
                s1[j] = *(const uint4*)(X + gX1[j] + k0);
            }
        }
        const u16* LA = &lds[cur][0][0];
        const u16* LB = &lds[cur][1 + wc][0];
#pragma unroll
        for (int ks = 0; ks < 2; ++ks) {
            bf16x8 a0 = *(const bf16x8*)(LA + arow[0] + cs[ks]);
            bf16x8 a1 = *(const bf16x8*)(LA + arow[1] + cs[ks]);
            bf16x8 bv[4];
#pragma unroll
            for (int f = 0; f < 4; ++f) bv[f] = *(const bf16x8*)(LB + brow[f] + cs[ks]);
#pragma unroll
            for (int f = 0; f < 4; ++f) {
                acc[0][f] = MFMA(a0, bv[f], acc[0][f]);
                acc[1][f] = MFMA(a1, bv[f], acc[1][f]);
            }
        }
        if (more) {
            const int nb = cur ^ 1;
#pragma unroll
            for (int j = 0; j < 2; ++j) {
                *(uint4*)(&lds[nb][0][j * 2048 + wofs]) = sA[j];
                *(uint4*)(&lds[nb][1][j * 2048 + wofs]) = s0[j];
                *(uint4*)(&lds[nb][2][j * 2048 + wofs]) = s1[j];
            }
        }
        __syncthreads();
        cur ^= 1;
    }

    const int g = g0 + wc;
    float* Tg = T + (size_t)g * NN * 64;
    const int row0 = bx * 64 + wr * 32;
#pragma unroll
    for (int m = 0; m < 2; ++m)
#pragma unroll
        for (int f = 0; f < 4; ++f)
#pragma unroll
            for (int r = 0; r < 4; ++r)
                Tg[(size_t)(row0 + m * 16 + l4 * 4 + r) * 64 + f * 16 + l15] = acc[m][f][r];
}

// ---------------- MLP core: out += relu(in@W1+b1)@W2 + b2 for 16 rows per wave ----------------
__device__ __forceinline__ void mlp_accum(
    const float* __restrict__ rowBase,   // in + (g*NN + n0)*64
    const u16* __restrict__ W1T, const u16* __restrict__ W2T,
    const float* __restrict__ b1, const float* __restrict__ b2,
    u16* __restrict__ my, int l15, int l4, f32x4 out[4])
{
    bf16x8 ain[2];
#pragma unroll
    for (int ks = 0; ks < 2; ++ks) {
        const float* p = rowBase + l15 * 64 + ks * 32 + l4 * 8;
        float4 u0 = *(const float4*)p;
        float4 u1 = *(const float4*)(p + 4);
        bf16x8 a;
        a[0] = (short)f2bf(u0.x); a[1] = (short)f2bf(u0.y); a[2] = (short)f2bf(u0.z); a[3] = (short)f2bf(u0.w);
        a[4] = (short)f2bf(u1.x); a[5] = (short)f2bf(u1.y); a[6] = (short)f2bf(u1.z); a[7] = (short)f2bf(u1.w);
        ain[ks] = a;
    }
    const f32x4 fz = {0.f, 0.f, 0.f, 0.f};
    f32x4 h[8];
#pragma unroll
    for (int o = 0; o < 8; ++o) h[o] = fz;
#pragma unroll
    for (int o = 0; o < 8; ++o)
#pragma unroll
        for (int ks = 0; ks < 2; ++ks) {
            bf16x8 w = *(const bf16x8*)(W1T + (o * 16 + l15) * 64 + ks * 32 + l4 * 8);
            h[o] = MFMA(ain[ks], w, h[o]);
        }
    // bias + relu -> LDS (swizzled) as a-fragments source
#pragma unroll
    for (int o = 0; o < 8; ++o) {
        float bb = b1[o * 16 + l15];
#pragma unroll
        for (int r = 0; r < 4; ++r) {
            int row = l4 * 4 + r, col = o * 16 + l15;
            int chunk = col >> 3;
            int idx = row * 128 + (((chunk ^ (row & 7))) << 3) + (col & 7);
            float v = h[o][r] + bb;
            my[idx] = f2bf(v > 0.f ? v : 0.f);
        }
    }
    asm volatile("s_waitcnt lgkmcnt(0)" ::: "memory");
#pragma unroll
    for (int ks = 0; ks < 4; ++ks) {
        int chunk = ks * 4 + l4;
        bf16x8 ah = *(const bf16x8*)(my + l15 * 128 + ((chunk ^ (l15 & 7)) << 3));
#pragma unroll
        for (int d = 0; d < 4; ++d) {
            bf16x8 w = *(const bf16x8*)(W2T + (d * 16 + l15) * 128 + ks * 32 + l4 * 8);
            out[d] = MFMA(ah, w, out[d]);
        }
    }
#pragma unroll
    for (int d = 0; d < 4; ++d) {
        float bb = b2[d * 16 + l15];
#pragma unroll
        for (int r = 0; r < 4; ++r) out[d][r] += bb;
    }
}

// MODE: 0 = B (out bx fp32 + yT = bx+cA), 1 = A (+bxF -> yT), 2 = D+E (s,z), 3 = D+cE (iter0), 4 = D final
template <int MODE>
__global__ __launch_bounds__(256) void k_mlp(
    const float* __restrict__ tIn, const float* __restrict__ tIn2,
    const float* __restrict__ addF, const float* __restrict__ cvecP,
    const float* __restrict__ alphaP,
    const u16* __restrict__ W1Ta, const u16* __restrict__ W2Ta,
    const float* __restrict__ b1a, const float* __restrict__ b2a,
    const u16* __restrict__ W1Tb, const u16* __restrict__ W2Tb,
    const float* __restrict__ b1b, const float* __restrict__ b2b,
    float* __restrict__ outF, u16* __restrict__ outT, u16* __restrict__ outT2)
{
    __shared__ __align__(16) u16 sl[4][2048];
    int tid = threadIdx.x, lane = tid & 63, wid = tid >> 6;
    int l15 = lane & 15, l4 = lane >> 4;
    int g = blockIdx.y;
    int n0 = blockIdx.x * 64 + wid * 16;
    u16* my = sl[wid];

    const f32x4 fz = {0.f, 0.f, 0.f, 0.f};
    f32x4 out[4];
#pragma unroll
    for (int d = 0; d < 4; ++d) out[d] = fz;

    mlp_accum(tIn + ((size_t)g * NN + n0) * 64, W1Ta, W2Ta, b1a, b2a, my, l15, l4, out);

    if constexpr (MODE == 2)
        mlp_accum(tIn2 + ((size_t)g * NN + n0) * 64, W1Tb, W2Tb, b1b, b2b, my, l15, l4, out);

    if constexpr (MODE == 3) {
#pragma unroll
        for (int d = 0; d < 4; ++d) {
            float cc = cvecP[64 + d * 16 + l15];
#pragma unroll
            for (int r = 0; r < 4; ++r) out[d][r] += cc;
        }
    }
    if constexpr (MODE == 1) {
#pragma unroll
        for (int d = 0; d < 4; ++d)
#pragma unroll
            for (int r = 0; r < 4; ++r)
                out[d][r] += addF[((size_t)g * NN + n0 + l4 * 4 + r) * 64 + d * 16 + l15];
    }

    if constexpr (MODE == 0 || MODE == 2 || MODE == 3 || MODE == 4) {
#pragma unroll
        for (int d = 0; d < 4; ++d)
#pragma unroll
            for (int r = 0; r < 4; ++r)
                outF[((size_t)g * NN + n0 + l4 * 4 + r) * 64 + d * 16 + l15] = out[d][r];
    }

    if constexpr (MODE == 0) {
#pragma unroll
        for (int d = 0; d < 4; ++d) {
            float cc = cvecP[d * 16 + l15];
#pragma unroll
            for (int r = 0; r < 4; ++r) out[d][r] += cc;
        }
        storeT16(outT, g, n0, my, lane, l15, l4, out);
    }
    if constexpr (MODE == 1) {
        storeT16(outT, g, n0, my, lane, l15, l4, out);
    }
    if constexpr (MODE == 2 || MODE == 3) {
        float al = alphaP[0];
        f32x4 zv[4];
#pragma unroll
        for (int d = 0; d < 4; ++d)
#pragma unroll
            for (int r = 0; r < 4; ++r) {
                float s = out[d][r];
                zv[d][r] = s > al ? (s - al) : (s < -al ? (s + al) : 0.f);
            }
        storeT16(outT, g, n0, my, lane, l15, l4, out);   // sT
        storeT16(outT2, g, n0, my, lane, l15, l4, zv);   // zT
    }
}

// ---------------- launch ----------------
extern "C" void kernel_launch(void* const* d_in, const int* in_sizes, int n_in,
                              void* d_out, int out_size, void* d_ws, size_t ws_size,
                              hipStream_t stream)
{
    const float* x_c   = (const float*)d_in[0];
    const float* Ain   = (const float*)d_in[1];
    const float* alpha = (const float*)d_in[2];
    const float* WA1 = (const float*)d_in[3],  *bA1 = (const float*)d_in[4];
    const float* WA2 = (const float*)d_in[5],  *bA2 = (const float*)d_in[6];
    const float* WB1 = (const float*)d_in[7],  *bB1 = (const float*)d_in[8];
    const float* WB2 = (const float*)d_in[9],  *bB2 = (const float*)d_in[10];
    const float* WD1 = (const float*)d_in[11], *bD1 = (const float*)d_in[12];
    const float* WD2 = (const float*)d_in[13], *bD2 = (const float*)d_in[14];
    const float* WE1 = (const float*)d_in[15], *bE1 = (const float*)d_in[16];
    const float* WE2 = (const float*)d_in[17], *bE2 = (const float*)d_in[18];

    char* ws = (char*)d_ws;
    const size_t OFF_ABF = 0;
    const size_t OFF_SZT = OFF_ABF + (size_t)NN * NN * 2;          // szT: [8][64][NN] bf16
    const size_t OFF_YT  = OFF_SZT + (size_t)8 * 64 * NN * 2;      // yT/xT: [4][64][NN] bf16
    const size_t OFF_TSZ = OFF_YT  + (size_t)4 * 64 * NN * 2;      // tSZ: [8][NN][64] f32
    const size_t OFF_TY  = OFF_TSZ + (size_t)8 * NN * 64 * 4;      // tY:  [4][NN][64] f32
    const size_t OFF_BX  = OFF_TY  + (size_t)4 * NN * 64 * 4;      // bxF: [4][NN][64] f32
    const size_t OFF_W1T = OFF_BX  + (size_t)4 * NN * 64 * 4;
    const size_t OFF_W2T = OFF_W1T + 65536;
    const size_t OFF_CV  = OFF_W2T + 65536;

    u16*   Abf  = (u16*)(ws + OFF_ABF);
    u16*   szT  = (u16*)(ws + OFF_SZT);
    u16*   zT   = szT + (size_t)4 * 64 * NN;
    u16*   yT   = (u16*)(ws + OFF_YT);
    float* tSZ  = (float*)(ws + OFF_TSZ);
    float* tZ   = tSZ + (size_t)4 * NN * 64;
    float* tY   = (float*)(ws + OFF_TY);
    float* bxF  = (float*)(ws + OFF_BX);
    u16*   W1T  = (u16*)(ws + OFF_W1T);
    u16*   W2T  = (u16*)(ws + OFF_W2T);
    float* cvec = (float*)(ws + OFF_CV);

    float* yOut = (float*)d_out;                 // y_c [4*8192*64]
    float* sF   = (float*)d_out + (size_t)4 * NN * 64;  // s

    const u16 *W1A = W1T, *W1B = W1T + 8192, *W1D = W1T + 16384, *W1E = W1T + 24576;
    const u16 *W2A = W2T, *W2B = W2T + 8192, *W2D = W2T + 16384, *W2E = W2T + 24576;

    k_cvtA<<<2048, 256, 0, stream>>>((const float4*)Ain, Abf);
    k_prep<<<1, 256, 0, stream>>>(WA1, WB1, WD1, WE1, WA2, WB2, WD2, WE2,
                                  bA1, bA2, bE1, bE2, W1T, W2T, cvec);
    k_trX<<<dim3(128, 4), 256, 0, stream>>>(x_c, yT);             // xT in yT buffer

    // bx = mlpB(A @ x); y0 = bx + cA  (mlpA(0) = cA since A@s0 = 0)
    k_gemm<<<dim3(128, 2), 256, 0, stream>>>(Abf, yT, tSZ);
    k_mlp<0><<<dim3(128, 4), 256, 0, stream>>>(tSZ, nullptr, nullptr, cvec, nullptr,
        W1B, W2B, bB1, bB2, nullptr, nullptr, nullptr, nullptr, bxF, yT, nullptr);

    // iter 0 tail: s = mlpD(A@y0) + cE ; z = soft(s)
    k_gemm<<<dim3(128, 2), 256, 0, stream>>>(Abf, yT, tY);
    k_mlp<3><<<dim3(128, 4), 256, 0, stream>>>(tY, nullptr, nullptr, cvec, alpha,
        W1D, W2D, bD1, bD2, nullptr, nullptr, nullptr, nullptr, sF, szT, zT);

    for (int it = 1; it < 8; ++it) {
        // [tS, tZ] = A @ [sT, zT]
        k_gemm<<<dim3(128, 4), 256, 0, stream>>>(Abf, szT, tSZ);
        // y = mlpA(tS) + bx
        k_mlp<1><<<dim3(128, 4), 256, 0, stream>>>(tSZ, nullptr, bxF, nullptr, nullptr,
            W1A, W2A, bA1, bA2, nullptr, nullptr, nullptr, nullptr, nullptr, yT, nullptr);
        // tY = A @ y
        k_gemm<<<dim3(128, 2), 256, 0, stream>>>(Abf, yT, tY);
        // s = mlpD(tY) + mlpE(tZ); z = soft(s)
        k_mlp<2><<<dim3(128, 4), 256, 0, stream>>>(tY, tZ, nullptr, nullptr, alpha,
            W1D, W2D, bD1, bD2, W1E, W2E, bE1, bE2, sF, szT, zT);
    }

    // y_c = mlpD(s)
    k_mlp<4><<<dim3(128, 4), 256, 0, stream>>>(sF, nullptr, nullptr, nullptr, nullptr,
        W1D, W2D, bD1, bD2, nullptr, nullptr, nullptr, nullptr, yOut, nullptr, nullptr);

    (void)in_sizes; (void)n_in; (void)out_size; (void)ws_size;
}